// Round 12
// baseline (31.617 us; speedup 1.0000x reference)
//
#include <hip/hip_runtime.h>
#include <hip/hip_bf16.h>

#define NR 512
#define DF 576
#define LOG2E 1.4426950408889634f

#if __has_builtin(__builtin_amdgcn_exp2f)
#define EXP2F __builtin_amdgcn_exp2f
#else
#define EXP2F exp2f
#endif

typedef _Float16 f16x8 __attribute__((ext_vector_type(8)));
typedef float f32x4 __attribute__((ext_vector_type(4)));

// Workspace: PT[kc(6)][w(3)][512][576] fp32 partials = 21,233,664 B
#define PT_OFF 0

// ---------------------------------------------------------------------------
// Kernel 1: QKV GEMM, direct-from-fp32, in-register fp16 conversion,
// LDS-free, split-K(6).  648 blocks x 512 thr (8 waves); wave job =
// (w, kc, rowt, colt): 32x32 output tile over K-chunk 96 (3 slices).
// Fragment assembly: lane reads row (base+(lane&15)), k = k0+(lane>>4)*8
// as two float4 from row-major fp32, converts to f16x8 (m89 frag layout).
// Per wave: 24 float4 loads + 96 cvt + 12 MFMA.  X/W fp32 are L2-resident.
// ---------------------------------------------------------------------------
__global__ __launch_bounds__(512) void qkv_direct_kernel(
    const float* __restrict__ X,
    const float* __restrict__ Wq, const float* __restrict__ Wk,
    const float* __restrict__ Wv,
    float* __restrict__ PT)
{
    const int wv   = threadIdx.x >> 6;
    const int lane = threadIdx.x & 63;
    const int job  = blockIdx.x * 8 + wv;          // 0..5183
    const int w    = job / 1728;
    int r = job - w * 1728;
    const int kc   = r / 288;  r -= kc * 288;
    const int rowt = r / 18;
    const int colt = r - rowt * 18;

    const float* W = (w == 0) ? Wq : (w == 1) ? Wk : Wv;

    const int lrow = lane & 15;
    const int kg   = (lane >> 4) * 8;
    const int k0   = kc * 96;

    const float* A0 = X + (size_t)(rowt * 32 + lrow) * DF;
    const float* A1 = A0 + 16 * DF;
    const float* B0 = W + (size_t)(colt * 32 + lrow) * DF;
    const float* B1 = B0 + 16 * DF;

    f32x4 acc[2][2] = {{{0.f,0.f,0.f,0.f},{0.f,0.f,0.f,0.f}},
                       {{0.f,0.f,0.f,0.f},{0.f,0.f,0.f,0.f}}};

#pragma unroll
    for (int s = 0; s < 3; ++s) {
        const int kk = k0 + s * 32 + kg;
        float4 va0 = *reinterpret_cast<const float4*>(A0 + kk);
        float4 va0b = *reinterpret_cast<const float4*>(A0 + kk + 4);
        float4 va1 = *reinterpret_cast<const float4*>(A1 + kk);
        float4 va1b = *reinterpret_cast<const float4*>(A1 + kk + 4);
        float4 vb0 = *reinterpret_cast<const float4*>(B0 + kk);
        float4 vb0b = *reinterpret_cast<const float4*>(B0 + kk + 4);
        float4 vb1 = *reinterpret_cast<const float4*>(B1 + kk);
        float4 vb1b = *reinterpret_cast<const float4*>(B1 + kk + 4);

        f16x8 fa0 = {(_Float16)va0.x, (_Float16)va0.y, (_Float16)va0.z, (_Float16)va0.w,
                     (_Float16)va0b.x, (_Float16)va0b.y, (_Float16)va0b.z, (_Float16)va0b.w};
        f16x8 fa1 = {(_Float16)va1.x, (_Float16)va1.y, (_Float16)va1.z, (_Float16)va1.w,
                     (_Float16)va1b.x, (_Float16)va1b.y, (_Float16)va1b.z, (_Float16)va1b.w};
        f16x8 fb0 = {(_Float16)vb0.x, (_Float16)vb0.y, (_Float16)vb0.z, (_Float16)vb0.w,
                     (_Float16)vb0b.x, (_Float16)vb0b.y, (_Float16)vb0b.z, (_Float16)vb0b.w};
        f16x8 fb1 = {(_Float16)vb1.x, (_Float16)vb1.y, (_Float16)vb1.z, (_Float16)vb1.w,
                     (_Float16)vb1b.x, (_Float16)vb1b.y, (_Float16)vb1b.z, (_Float16)vb1b.w};

        acc[0][0] = __builtin_amdgcn_mfma_f32_16x16x32_f16(fa0, fb0, acc[0][0], 0, 0, 0);
        acc[0][1] = __builtin_amdgcn_mfma_f32_16x16x32_f16(fa0, fb1, acc[0][1], 0, 0, 0);
        acc[1][0] = __builtin_amdgcn_mfma_f32_16x16x32_f16(fa1, fb0, acc[1][0], 0, 0, 0);
        acc[1][1] = __builtin_amdgcn_mfma_f32_16x16x32_f16(fa1, fb1, acc[1][1], 0, 0, 0);
    }

    float* P = PT + (size_t)(kc * 3 + w) * NR * DF;
#pragma unroll
    for (int ni = 0; ni < 2; ++ni) {
        const int col = colt * 32 + ni * 16 + (lane & 15);
#pragma unroll
        for (int mi = 0; mi < 2; ++mi) {
            const int row0 = rowt * 32 + mi * 16 + (lane >> 4) * 4;
#pragma unroll
            for (int rr = 0; rr < 4; ++rr)
                P[(size_t)(row0 + rr) * DF + col] = acc[mi][ni][rr];
        }
    }
}

// ---------------------------------------------------------------------------
// Kernel 2: rank-1 attention via tilted-mean interpolation; fused 6-way
// split-K reduce (+bias).  Same structure as R11 (36 nodes, 16 chunks).
// ---------------------------------------------------------------------------
#define M_NODES 36
#define CHUNKS  16
#define JPC     36
#define CSTRIDE 19

__global__ __launch_bounds__(576) void attn_interp_kernel(
    const float* __restrict__ PT,
    const float* __restrict__ bq, const float* __restrict__ bk,
    const float* __restrict__ bv,
    float* __restrict__ out)
{
    const int n = blockIdx.x;
    const int t = threadIdx.x;
    const size_t nb = (size_t)n * DF + t;
    const size_t pl = (size_t)NR * DF;

    float qv = bq[t], kv = bk[t], vv = bv[t];
#pragma unroll
    for (int kc = 0; kc < 6; ++kc) {
        qv += PT[pl * (kc * 3 + 0) + nb];
        kv += PT[pl * (kc * 3 + 1) + nb];
        vv += PT[pl * (kc * 3 + 2) + nb];
    }

    __shared__ __align__(16) float4 KV4[CHUNKS * CSTRIDE];
    __shared__ __align__(16) float Pf[DF];
    __shared__ __align__(16) float Pg[DF];
    __shared__ float Rt[M_NODES];
    __shared__ float range[2];

    {
        const int c  = t / JPC;
        const int jl = t - c * JPC;
        float2* dst = reinterpret_cast<float2*>(&KV4[c * CSTRIDE + (jl >> 1)]);
        dst[jl & 1] = make_float2(kv * LOG2E, vv);
    }
    Pf[t] = qv;
    __syncthreads();

    if (t < 64) {
        float lo = Pf[t], hi = lo;
#pragma unroll
        for (int r = 1; r < 9; ++r) {
            float v = Pf[t + 64 * r];
            lo = fminf(lo, v); hi = fmaxf(hi, v);
        }
#pragma unroll
        for (int s = 32; s; s >>= 1) {
            lo = fminf(lo, __shfl_xor(lo, s, 64));
            hi = fmaxf(hi, __shfl_xor(hi, s, 64));
        }
        if (t == 0) { range[0] = lo; range[1] = hi; }
    }
    __syncthreads();

    const float qmin = range[0], qmax = range[1];
    const float h    = fmaxf((qmax - qmin) * (1.0f / (M_NODES - 5)), 1e-6f);
    const float qlo  = qmin - 2.0f * h;

    const int m = t >> 4;
    const int c = t & 15;
    const float qm = qlo + h * (float)m;
    const float4* kvp = KV4 + c * CSTRIDE;
    float f0 = 0.f, f1 = 0.f, g0 = 0.f, g1 = 0.f;
#pragma unroll
    for (int jj = 0; jj < JPC / 2; ++jj) {
        float4 p = kvp[jj];
        float e0 = EXP2F(qm * p.x);
        float e1 = EXP2F(qm * p.z);
        g0 += e0; g1 += e1;
        f0 = fmaf(e0, p.y, f0);
        f1 = fmaf(e1, p.w, f1);
    }
    __syncthreads();
    Pf[t] = f0 + f1;
    Pg[t] = g0 + g1;
    __syncthreads();

    if (t < M_NODES) {
        const float4* pf4 = reinterpret_cast<const float4*>(Pf) + t * 4;
        const float4* pg4 = reinterpret_cast<const float4*>(Pg) + t * 4;
        float fs = 0.f, gs = 0.f;
#pragma unroll
        for (int i = 0; i < 4; ++i) {
            float4 a = pf4[i], b = pg4[i];
            fs += (a.x + a.y) + (a.z + a.w);
            gs += (b.x + b.y) + (b.z + b.w);
        }
        Rt[t] = fs / gs;
    }
    __syncthreads();

    const float u = (qv - qlo) * (1.0f / h);
    int i0 = (int)u;
    i0 = (i0 < 1) ? 1 : (i0 > M_NODES - 3 ? M_NODES - 3 : i0);
    const float tf = u - (float)i0;
    const float a  = Rt[i0 - 1];
    const float b  = Rt[i0];
    const float cc = Rt[i0 + 1];
    const float d  = Rt[i0 + 2];
    const float m0 = 0.5f * (cc - a);
    const float m1 = 0.5f * (d - b);
    const float dd = cc - b;
    const float r  = b + tf * (m0 + tf * ((3.f * dd - 2.f * m0 - m1)
                                          + tf * (m0 + m1 - 2.f * dd)));
    out[(size_t)n * DF + t] = r;
}

// ---------------------------------------------------------------------------
extern "C" void kernel_launch(void* const* d_in, const int* in_sizes, int n_in,
                              void* d_out, int out_size, void* d_ws, size_t ws_size,
                              hipStream_t stream) {
    const float* x  = (const float*)d_in[0];
    const float* Wq = (const float*)d_in[1];
    const float* bq = (const float*)d_in[2];
    const float* Wk = (const float*)d_in[3];
    const float* bk = (const float*)d_in[4];
    const float* Wv = (const float*)d_in[5];
    const float* bv = (const float*)d_in[6];

    float* PT = (float*)((char*)d_ws + PT_OFF);

    qkv_direct_kernel<<<648, 512, 0, stream>>>(x, Wq, Wk, Wv, PT);

    attn_interp_kernel<<<NR, DF, 0, stream>>>(PT, bq, bk, bv, (float*)d_out);
}

// Round 13
// 26.556 us; speedup vs baseline: 1.1906x; 1.1906x over previous
//
#include <hip/hip_runtime.h>
#include <hip/hip_bf16.h>

#define NR 512
#define DF 576
#define LOG2E 1.4426950408889634f

#if __has_builtin(__builtin_amdgcn_exp2f)
#define EXP2F __builtin_amdgcn_exp2f
#else
#define EXP2F exp2f
#endif

typedef _Float16 f16x8 __attribute__((ext_vector_type(8)));
typedef float f32x4 __attribute__((ext_vector_type(4)));
typedef unsigned short u16x8 __attribute__((ext_vector_type(8)));

// Workspace layout (bytes):
//  PT[kc(6)][w(3)][512][576] fp32 partials : 21,233,664
//  XF fp16 frag plane                      : 589,824
//  WF fp16 frag plane (3 w's)              : 1,990,656
#define PT_OFF  0
#define XF_OFF  21233664
#define WF_OFF  21823488
#define WF_PER_W 331776        // elems per w (36*18*64*8)

// ---------------------------------------------------------------------------
// Kernel 0: fp32 -> fp16 planes in MFMA fragment order (unchanged from R11).
//   fr=row>>4, ks=k>>5, lane=(row&15)+16*((k&31)>>3), j=k&7
// ---------------------------------------------------------------------------
__global__ __launch_bounds__(256) void prep_f16_kernel(
    const float* __restrict__ X,
    const float* __restrict__ Wq, const float* __restrict__ Wk,
    const float* __restrict__ Wv,
    unsigned short* __restrict__ XF, unsigned short* __restrict__ WF)
{
    const int z = blockIdx.y;
    const float* src; unsigned short* d; int n8;
    if (z == 0) { src = X; d = XF; n8 = (NR * DF) / 8; }
    else {
        src = (z == 1) ? Wq : (z == 2) ? Wk : Wv;
        d = WF + (size_t)(z - 1) * WF_PER_W;
        n8 = (DF * DF) / 8;
    }
    const int i = blockIdx.x * 256 + threadIdx.x;
    if (i >= n8) return;

    const int flat = i * 8;
    const int row  = flat / DF;
    const int k    = flat - row * DF;
    const int fr   = row >> 4;
    const int ks   = k >> 5;
    const int lane = (row & 15) + 16 * ((k & 31) >> 3);
    const int off  = ((fr * 18 + ks) * 64 + lane) * 8;

    const float4 v0 = *reinterpret_cast<const float4*>(src + (size_t)row * DF + k);
    const float4 v1 = *reinterpret_cast<const float4*>(src + (size_t)row * DF + k + 4);
    float fv[8] = {v0.x, v0.y, v0.z, v0.w, v1.x, v1.y, v1.z, v1.w};
    u16x8 h;
#pragma unroll
    for (int e = 0; e < 8; ++e)
        h[e] = __builtin_bit_cast(unsigned short, (_Float16)fv[e]);
    *reinterpret_cast<u16x8*>(d + off) = h;
}

// ---------------------------------------------------------------------------
// Kernel 1: QKV GEMM, fp16 planes, LDS-free, SPLIT-K(6).
// Grid (9,8,18): z = w*6+kc; 256 thr = 4 waves 2x2.  Per wave: 32x32 tile
// over K-chunk 96 = 3 slices x {4 b128 loads + 4 MFMA, 4 indep chains}.
// 5184 wave-jobs = 20 waves/CU (vs 10 at kc=3): latency-hiding x2 with
// IDENTICAL total load traffic (63.7 MB); only PT write doubles.
// ---------------------------------------------------------------------------
__global__ __launch_bounds__(256) void qkv_f16_splitk_kernel(
    const unsigned short* __restrict__ XF, const unsigned short* __restrict__ WF,
    float* __restrict__ PT)
{
    const int w  = blockIdx.z / 6;
    const int kc = blockIdx.z - w * 6;
    const int tid  = threadIdx.x;
    const int lane = tid & 63;
    const int wv   = tid >> 6;
    const int rowt = blockIdx.y * 2 + (wv >> 1);   // 0..15
    const int colt = blockIdx.x * 2 + (wv & 1);    // 0..17

    const unsigned short* wf = WF + (size_t)w * WF_PER_W;

    const int kbase = kc * 3 * 512;                // 3 slices per chunk
    const int a0 = (rowt * 2    ) * 9216 + kbase + lane * 8;
    const int a1 = (rowt * 2 + 1) * 9216 + kbase + lane * 8;
    const int b0 = (colt * 2    ) * 9216 + kbase + lane * 8;
    const int b1 = (colt * 2 + 1) * 9216 + kbase + lane * 8;

    f32x4 acc[2][2] = {{{0.f,0.f,0.f,0.f},{0.f,0.f,0.f,0.f}},
                       {{0.f,0.f,0.f,0.f},{0.f,0.f,0.f,0.f}}};

#pragma unroll
    for (int s = 0; s < 3; ++s) {
        const int o = s * 512;
        f16x8 fa0 = *reinterpret_cast<const f16x8*>(XF + a0 + o);
        f16x8 fa1 = *reinterpret_cast<const f16x8*>(XF + a1 + o);
        f16x8 fb0 = *reinterpret_cast<const f16x8*>(wf + b0 + o);
        f16x8 fb1 = *reinterpret_cast<const f16x8*>(wf + b1 + o);
        acc[0][0] = __builtin_amdgcn_mfma_f32_16x16x32_f16(fa0, fb0, acc[0][0], 0, 0, 0);
        acc[0][1] = __builtin_amdgcn_mfma_f32_16x16x32_f16(fa0, fb1, acc[0][1], 0, 0, 0);
        acc[1][0] = __builtin_amdgcn_mfma_f32_16x16x32_f16(fa1, fb0, acc[1][0], 0, 0, 0);
        acc[1][1] = __builtin_amdgcn_mfma_f32_16x16x32_f16(fa1, fb1, acc[1][1], 0, 0, 0);
    }

    float* P = PT + (size_t)(kc * 3 + w) * NR * DF;
#pragma unroll
    for (int ni = 0; ni < 2; ++ni) {
        const int col = colt * 32 + ni * 16 + (lane & 15);
#pragma unroll
        for (int mi = 0; mi < 2; ++mi) {
            const int row0 = rowt * 32 + mi * 16 + (lane >> 4) * 4;
#pragma unroll
            for (int r = 0; r < 4; ++r)
                P[(size_t)(row0 + r) * DF + col] = acc[mi][ni][r];
        }
    }
}

// ---------------------------------------------------------------------------
// Kernel 2: rank-1 attention via tilted-mean interpolation; fused 6-way
// split-K reduce (+bias).  36 nodes x 16 chunks (same as R11).
// ---------------------------------------------------------------------------
#define M_NODES 36
#define CHUNKS  16
#define JPC     36
#define CSTRIDE 19

__global__ __launch_bounds__(576) void attn_interp_kernel(
    const float* __restrict__ PT,
    const float* __restrict__ bq, const float* __restrict__ bk,
    const float* __restrict__ bv,
    float* __restrict__ out)
{
    const int n = blockIdx.x;
    const int t = threadIdx.x;
    const size_t nb = (size_t)n * DF + t;
    const size_t pl = (size_t)NR * DF;

    float qv = bq[t], kv = bk[t], vv = bv[t];
#pragma unroll
    for (int kc = 0; kc < 6; ++kc) {
        qv += PT[pl * (kc * 3 + 0) + nb];
        kv += PT[pl * (kc * 3 + 1) + nb];
        vv += PT[pl * (kc * 3 + 2) + nb];
    }

    __shared__ __align__(16) float4 KV4[CHUNKS * CSTRIDE];
    __shared__ __align__(16) float Pf[DF];
    __shared__ __align__(16) float Pg[DF];
    __shared__ float Rt[M_NODES];
    __shared__ float range[2];

    {
        const int c  = t / JPC;
        const int jl = t - c * JPC;
        float2* dst = reinterpret_cast<float2*>(&KV4[c * CSTRIDE + (jl >> 1)]);
        dst[jl & 1] = make_float2(kv * LOG2E, vv);
    }
    Pf[t] = qv;
    __syncthreads();

    if (t < 64) {
        float lo = Pf[t], hi = lo;
#pragma unroll
        for (int r = 1; r < 9; ++r) {
            float v = Pf[t + 64 * r];
            lo = fminf(lo, v); hi = fmaxf(hi, v);
        }
#pragma unroll
        for (int s = 32; s; s >>= 1) {
            lo = fminf(lo, __shfl_xor(lo, s, 64));
            hi = fmaxf(hi, __shfl_xor(hi, s, 64));
        }
        if (t == 0) { range[0] = lo; range[1] = hi; }
    }
    __syncthreads();

    const float qmin = range[0], qmax = range[1];
    const float h    = fmaxf((qmax - qmin) * (1.0f / (M_NODES - 5)), 1e-6f);
    const float qlo  = qmin - 2.0f * h;

    const int m = t >> 4;
    const int c = t & 15;
    const float qm = qlo + h * (float)m;
    const float4* kvp = KV4 + c * CSTRIDE;
    float f0 = 0.f, f1 = 0.f, g0 = 0.f, g1 = 0.f;
#pragma unroll
    for (int jj = 0; jj < JPC / 2; ++jj) {
        float4 p = kvp[jj];
        float e0 = EXP2F(qm * p.x);
        float e1 = EXP2F(qm * p.z);
        g0 += e0; g1 += e1;
        f0 = fmaf(e0, p.y, f0);
        f1 = fmaf(e1, p.w, f1);
    }
    __syncthreads();
    Pf[t] = f0 + f1;
    Pg[t] = g0 + g1;
    __syncthreads();

    if (t < M_NODES) {
        const float4* pf4 = reinterpret_cast<const float4*>(Pf) + t * 4;
        const float4* pg4 = reinterpret_cast<const float4*>(Pg) + t * 4;
        float fs = 0.f, gs = 0.f;
#pragma unroll
        for (int i = 0; i < 4; ++i) {
            float4 a = pf4[i], b = pg4[i];
            fs += (a.x + a.y) + (a.z + a.w);
            gs += (b.x + b.y) + (b.z + b.w);
        }
        Rt[t] = fs / gs;
    }
    __syncthreads();

    const float u = (qv - qlo) * (1.0f / h);
    int i0 = (int)u;
    i0 = (i0 < 1) ? 1 : (i0 > M_NODES - 3 ? M_NODES - 3 : i0);
    const float tf = u - (float)i0;
    const float a  = Rt[i0 - 1];
    const float b  = Rt[i0];
    const float cc = Rt[i0 + 1];
    const float d  = Rt[i0 + 2];
    const float m0 = 0.5f * (cc - a);
    const float m1 = 0.5f * (d - b);
    const float dd = cc - b;
    const float r  = b + tf * (m0 + tf * ((3.f * dd - 2.f * m0 - m1)
                                          + tf * (m0 + m1 - 2.f * dd)));
    out[(size_t)n * DF + t] = r;
}

// ---------------------------------------------------------------------------
extern "C" void kernel_launch(void* const* d_in, const int* in_sizes, int n_in,
                              void* d_out, int out_size, void* d_ws, size_t ws_size,
                              hipStream_t stream) {
    const float* x  = (const float*)d_in[0];
    const float* Wq = (const float*)d_in[1];
    const float* bq = (const float*)d_in[2];
    const float* Wk = (const float*)d_in[3];
    const float* bk = (const float*)d_in[4];
    const float* Wv = (const float*)d_in[5];
    const float* bv = (const float*)d_in[6];

    char* ws = (char*)d_ws;
    float*          PT = (float*)(ws + PT_OFF);
    unsigned short* XF = (unsigned short*)(ws + XF_OFF);
    unsigned short* WF = (unsigned short*)(ws + WF_OFF);

    prep_f16_kernel<<<dim3(162, 4, 1), 256, 0, stream>>>(
        x, Wq, Wk, Wv, XF, WF);

    qkv_f16_splitk_kernel<<<dim3(9, 8, 18), 256, 0, stream>>>(XF, WF, PT);

    attn_interp_kernel<<<NR, DF, 0, stream>>>(PT, bq, bk, bv, (float*)d_out);
}

// Round 14
// 23.999 us; speedup vs baseline: 1.3174x; 1.1065x over previous
//
#include <hip/hip_runtime.h>
#include <hip/hip_bf16.h>

#define NR 512
#define DF 576
#define LOG2E 1.4426950408889634f

#if __has_builtin(__builtin_amdgcn_exp2f)
#define EXP2F __builtin_amdgcn_exp2f
#else
#define EXP2F exp2f
#endif

typedef _Float16 f16x8 __attribute__((ext_vector_type(8)));
typedef float f32x4 __attribute__((ext_vector_type(4)));
typedef unsigned short u16x8 __attribute__((ext_vector_type(8)));

// Workspace layout (bytes):
//  PT[kc(3)][w(3)][512][576] fp32 partials : 10,616,832
//  XF fp16 frag plane                      : 589,824
//  WF fp16 frag plane (3 w's)              : 1,990,656
#define PT_OFF  0
#define XF_OFF  10616832
#define WF_OFF  11206656
#define WF_PER_W 331776        // elems per w (36*18*64*8)

// ---------------------------------------------------------------------------
// Kernel 0: fp32 -> fp16 planes in MFMA fragment order (unchanged from R11).
// ---------------------------------------------------------------------------
__global__ __launch_bounds__(256) void prep_f16_kernel(
    const float* __restrict__ X,
    const float* __restrict__ Wq, const float* __restrict__ Wk,
    const float* __restrict__ Wv,
    unsigned short* __restrict__ XF, unsigned short* __restrict__ WF)
{
    const int z = blockIdx.y;
    const float* src; unsigned short* d; int n8;
    if (z == 0) { src = X; d = XF; n8 = (NR * DF) / 8; }
    else {
        src = (z == 1) ? Wq : (z == 2) ? Wk : Wv;
        d = WF + (size_t)(z - 1) * WF_PER_W;
        n8 = (DF * DF) / 8;
    }
    const int i = blockIdx.x * 256 + threadIdx.x;
    if (i >= n8) return;

    const int flat = i * 8;
    const int row  = flat / DF;
    const int k    = flat - row * DF;
    const int fr   = row >> 4;
    const int ks   = k >> 5;
    const int lane = (row & 15) + 16 * ((k & 31) >> 3);
    const int off  = ((fr * 18 + ks) * 64 + lane) * 8;

    const float4 v0 = *reinterpret_cast<const float4*>(src + (size_t)row * DF + k);
    const float4 v1 = *reinterpret_cast<const float4*>(src + (size_t)row * DF + k + 4);
    float fv[8] = {v0.x, v0.y, v0.z, v0.w, v1.x, v1.y, v1.z, v1.w};
    u16x8 h;
#pragma unroll
    for (int e = 0; e < 8; ++e)
        h[e] = __builtin_bit_cast(unsigned short, (_Float16)fv[e]);
    *reinterpret_cast<u16x8*>(d + off) = h;
}

// ---------------------------------------------------------------------------
// Kernel 1: QKV GEMM, fp16 planes, LDS-free, split-K(3), LOAD-FIRST.
// Grid (9,8,9) z=w*3+kc; 256 thr = 4 waves 2x2.  Per wave: 32x32 tile over
// K-chunk 192.  ALL 24 b128 loads issued first (96 VGPR, static unroll),
// then all 24 MFMAs: one L2-latency exposure instead of six chained.
// ---------------------------------------------------------------------------
__global__ __launch_bounds__(256) void qkv_f16_splitk_kernel(
    const unsigned short* __restrict__ XF, const unsigned short* __restrict__ WF,
    float* __restrict__ PT)
{
    const int w  = blockIdx.z / 3;
    const int kc = blockIdx.z - w * 3;
    const int tid  = threadIdx.x;
    const int lane = tid & 63;
    const int wv   = tid >> 6;
    const int rowt = blockIdx.y * 2 + (wv >> 1);   // 0..15
    const int colt = blockIdx.x * 2 + (wv & 1);    // 0..17

    const unsigned short* wf = WF + (size_t)w * WF_PER_W;

    const int kbase = kc * 6 * 512;
    const int a0 = (rowt * 2    ) * 9216 + kbase + lane * 8;
    const int a1 = (rowt * 2 + 1) * 9216 + kbase + lane * 8;
    const int b0 = (colt * 2    ) * 9216 + kbase + lane * 8;
    const int b1 = (colt * 2 + 1) * 9216 + kbase + lane * 8;

    // phase 1: issue ALL loads (fully unrolled, static indices -> registers)
    f16x8 fa0[6], fa1[6], fb0[6], fb1[6];
#pragma unroll
    for (int s = 0; s < 6; ++s) {
        const int o = s * 512;
        fa0[s] = *reinterpret_cast<const f16x8*>(XF + a0 + o);
        fa1[s] = *reinterpret_cast<const f16x8*>(XF + a1 + o);
        fb0[s] = *reinterpret_cast<const f16x8*>(wf + b0 + o);
        fb1[s] = *reinterpret_cast<const f16x8*>(wf + b1 + o);
    }

    // phase 2: all MFMAs (4 independent accumulator chains)
    f32x4 acc[2][2] = {{{0.f,0.f,0.f,0.f},{0.f,0.f,0.f,0.f}},
                       {{0.f,0.f,0.f,0.f},{0.f,0.f,0.f,0.f}}};
#pragma unroll
    for (int s = 0; s < 6; ++s) {
        acc[0][0] = __builtin_amdgcn_mfma_f32_16x16x32_f16(fa0[s], fb0[s], acc[0][0], 0, 0, 0);
        acc[0][1] = __builtin_amdgcn_mfma_f32_16x16x32_f16(fa0[s], fb1[s], acc[0][1], 0, 0, 0);
        acc[1][0] = __builtin_amdgcn_mfma_f32_16x16x32_f16(fa1[s], fb0[s], acc[1][0], 0, 0, 0);
        acc[1][1] = __builtin_amdgcn_mfma_f32_16x16x32_f16(fa1[s], fb1[s], acc[1][1], 0, 0, 0);
    }

    float* P = PT + (size_t)(kc * 3 + w) * NR * DF;
#pragma unroll
    for (int ni = 0; ni < 2; ++ni) {
        const int col = colt * 32 + ni * 16 + (lane & 15);
#pragma unroll
        for (int mi = 0; mi < 2; ++mi) {
            const int row0 = rowt * 32 + mi * 16 + (lane >> 4) * 4;
#pragma unroll
            for (int r = 0; r < 4; ++r)
                P[(size_t)(row0 + r) * DF + col] = acc[mi][ni][r];
        }
    }
}

// ---------------------------------------------------------------------------
// Kernel 2: rank-1 attention via tilted-mean interpolation; fused 3-way
// split-K reduce (+bias).  Byte-identical to R11.
// ---------------------------------------------------------------------------
#define M_NODES 36
#define CHUNKS  16
#define JPC     36
#define CSTRIDE 19

__global__ __launch_bounds__(576) void attn_interp_kernel(
    const float* __restrict__ PT,
    const float* __restrict__ bq, const float* __restrict__ bk,
    const float* __restrict__ bv,
    float* __restrict__ out)
{
    const int n = blockIdx.x;
    const int t = threadIdx.x;
    const size_t nb = (size_t)n * DF + t;
    const size_t pl = (size_t)NR * DF;

    const float qv = ((PT[nb] + PT[pl * 3 + nb]) + PT[pl * 6 + nb]) + bq[t];
    const float kv = ((PT[pl + nb] + PT[pl * 4 + nb]) + PT[pl * 7 + nb]) + bk[t];
    const float vv = ((PT[pl * 2 + nb] + PT[pl * 5 + nb]) + PT[pl * 8 + nb]) + bv[t];

    __shared__ __align__(16) float4 KV4[CHUNKS * CSTRIDE];
    __shared__ __align__(16) float Pf[DF];
    __shared__ __align__(16) float Pg[DF];
    __shared__ float Rt[M_NODES];
    __shared__ float range[2];

    {
        const int c  = t / JPC;
        const int jl = t - c * JPC;
        float2* dst = reinterpret_cast<float2*>(&KV4[c * CSTRIDE + (jl >> 1)]);
        dst[jl & 1] = make_float2(kv * LOG2E, vv);
    }
    Pf[t] = qv;
    __syncthreads();

    if (t < 64) {
        float lo = Pf[t], hi = lo;
#pragma unroll
        for (int r = 1; r < 9; ++r) {
            float v = Pf[t + 64 * r];
            lo = fminf(lo, v); hi = fmaxf(hi, v);
        }
#pragma unroll
        for (int s = 32; s; s >>= 1) {
            lo = fminf(lo, __shfl_xor(lo, s, 64));
            hi = fmaxf(hi, __shfl_xor(hi, s, 64));
        }
        if (t == 0) { range[0] = lo; range[1] = hi; }
    }
    __syncthreads();

    const float qmin = range[0], qmax = range[1];
    const float h    = fmaxf((qmax - qmin) * (1.0f / (M_NODES - 5)), 1e-6f);
    const float qlo  = qmin - 2.0f * h;

    const int m = t >> 4;
    const int c = t & 15;
    const float qm = qlo + h * (float)m;
    const float4* kvp = KV4 + c * CSTRIDE;
    float f0 = 0.f, f1 = 0.f, g0 = 0.f, g1 = 0.f;
#pragma unroll
    for (int jj = 0; jj < JPC / 2; ++jj) {
        float4 p = kvp[jj];
        float e0 = EXP2F(qm * p.x);
        float e1 = EXP2F(qm * p.z);
        g0 += e0; g1 += e1;
        f0 = fmaf(e0, p.y, f0);
        f1 = fmaf(e1, p.w, f1);
    }
    __syncthreads();
    Pf[t] = f0 + f1;
    Pg[t] = g0 + g1;
    __syncthreads();

    if (t < M_NODES) {
        const float4* pf4 = reinterpret_cast<const float4*>(Pf) + t * 4;
        const float4* pg4 = reinterpret_cast<const float4*>(Pg) + t * 4;
        float fs = 0.f, gs = 0.f;
#pragma unroll
        for (int i = 0; i < 4; ++i) {
            float4 a = pf4[i], b = pg4[i];
            fs += (a.x + a.y) + (a.z + a.w);
            gs += (b.x + b.y) + (b.z + b.w);
        }
        Rt[t] = fs / gs;
    }
    __syncthreads();

    const float u = (qv - qlo) * (1.0f / h);
    int i0 = (int)u;
    i0 = (i0 < 1) ? 1 : (i0 > M_NODES - 3 ? M_NODES - 3 : i0);
    const float tf = u - (float)i0;
    const float a  = Rt[i0 - 1];
    const float b  = Rt[i0];
    const float cc = Rt[i0 + 1];
    const float d  = Rt[i0 + 2];
    const float m0 = 0.5f * (cc - a);
    const float m1 = 0.5f * (d - b);
    const float dd = cc - b;
    const float r  = b + tf * (m0 + tf * ((3.f * dd - 2.f * m0 - m1)
                                          + tf * (m0 + m1 - 2.f * dd)));
    out[(size_t)n * DF + t] = r;
}

// ---------------------------------------------------------------------------
extern "C" void kernel_launch(void* const* d_in, const int* in_sizes, int n_in,
                              void* d_out, int out_size, void* d_ws, size_t ws_size,
                              hipStream_t stream) {
    const float* x  = (const float*)d_in[0];
    const float* Wq = (const float*)d_in[1];
    const float* bq = (const float*)d_in[2];
    const float* Wk = (const float*)d_in[3];
    const float* bk = (const float*)d_in[4];
    const float* Wv = (const float*)d_in[5];
    const float* bv = (const float*)d_in[6];

    char* ws = (char*)d_ws;
    float*          PT = (float*)(ws + PT_OFF);
    unsigned short* XF = (unsigned short*)(ws + XF_OFF);
    unsigned short* WF = (unsigned short*)(ws + WF_OFF);

    prep_f16_kernel<<<dim3(162, 4, 1), 256, 0, stream>>>(
        x, Wq, Wk, Wv, XF, WF);

    qkv_f16_splitk_kernel<<<dim3(9, 8, 9), 256, 0, stream>>>(XF, WF, PT);

    attn_interp_kernel<<<NR, DF, 0, stream>>>(PT, bq, bk, bv, (float*)d_out);
}